// Round 9
// baseline (3766.337 us; speedup 1.0000x reference)
//
#include <hip/hip_runtime.h>
#include <hip/hip_bf16.h>

typedef __hip_bfloat16 bf16;
typedef unsigned short u16;
typedef unsigned int u32;
typedef unsigned char u8;
typedef __attribute__((ext_vector_type(8))) short bf16x8;
typedef __attribute__((ext_vector_type(4))) float f32x4;

#define NB 8
#define CH 192
#define WSZ (CH*CH*9)

// Activations are channels-last: A[b][y][x][c], bf16.

static __device__ __forceinline__ float bf2f(bf16 v){ return __bfloat162float(v); }
static __device__ __forceinline__ u16 f2bu(float f){
  union { bf16 h; u16 u; } cv; cv.h = __float2bfloat16(f); return cv.u;
}

// ---------------- utility kernels ----------------

__global__ void k_zero(float* p, int n){
  int i = blockIdx.x*blockDim.x + threadIdx.x;
  if(i < n) p[i] = 0.f;
}

__global__ void k_fill(float* p, int n, float v){
  int i = blockIdx.x*blockDim.x + threadIdx.x;
  if(i < n) p[i] = v;
}

__global__ void k_mask0(const int* __restrict__ mask, u8* __restrict__ m0){
  int i = blockIdx.x*blockDim.x + threadIdx.x;
  if(i >= NB*65536) return;
  int b = i >> 16; int p = i & 65535;
  int y = p >> 8, x = p & 255;
  int patch = (y >> 4)*16 + (x >> 4);
  m0[i] = (u8)(1 - mask[b*256 + patch]);
}

__global__ void k_maskdown(const u8* __restrict__ mi, u8* __restrict__ mo,
                           int Ho, int Wo, int Hi, int Wi){
  int i = blockIdx.x*blockDim.x + threadIdx.x;
  int total = NB*Ho*Wo; if(i >= total) return;
  int b = i/(Ho*Wo); int p = i%(Ho*Wo);
  int oy = p/Wo, ox = p%Wo;
  u8 v = 0;
  for(int ky=0; ky<3; ky++){
    int iy = oy*2 + ky - 1; if(iy < 0 || iy >= Hi) continue;
    for(int kx=0; kx<3; kx++){
      int ix = ox*2 + kx - 1; if(ix < 0 || ix >= Wi) continue;
      u8 t = mi[(b*Hi + iy)*Wi + ix]; if(t > v) v = t;
    }
  }
  mo[i] = v;
}

__global__ void k_count(const u8* __restrict__ m, int n, float* cnt){
  int i = blockIdx.x*blockDim.x + threadIdx.x;
  int stride = gridDim.x*blockDim.x;
  int local = 0;
  for(int j=i; j<n; j+=stride) local += m[j];
  for(int o=32; o>0; o>>=1) local += __shfl_down(local, o, 64);
  if((threadIdx.x & 63) == 0 && local) atomicAdd(cnt, (float)local);
}

// ---------------- stem BN stats (images NCHW f32) ----------------

__global__ __launch_bounds__(256) void k_stemstats2(const float* __restrict__ im,
        const u8* __restrict__ m0, const float* __restrict__ sw,
        float* __restrict__ stats){
  int c = blockIdx.x;
  int chunk = blockIdx.y;
  float w0 = sw[c*3+0], w1 = sw[c*3+1], w2 = sw[c*3+2];
  float s = 0.f, s2 = 0.f;
  int start = chunk*4096;
  for(int j = start + threadIdx.x; j < start + 4096; j += 256){
    if(m0[j]){
      int b = j >> 16, p = j & 65535;
      float d = w0*im[(size_t)(b*3+0)*65536 + p]
              + w1*im[(size_t)(b*3+1)*65536 + p]
              + w2*im[(size_t)(b*3+2)*65536 + p];
      s += d; s2 += d*d;
    }
  }
  for(int o=32; o>0; o>>=1){ s += __shfl_down(s, o, 64); s2 += __shfl_down(s2, o, 64); }
  __shared__ float sh[8];
  int w = threadIdx.x >> 6;
  if((threadIdx.x & 63) == 0){ sh[w] = s; sh[4+w] = s2; }
  __syncthreads();
  if(threadIdx.x == 0){
    float ts = 0.f, t2 = 0.f;
    for(int k=0;k<4;k++){ ts += sh[k]; t2 += sh[4+k]; }
    atomicAdd(&stats[c], ts);
    atomicAdd(&stats[CH + c], t2);
  }
}

__global__ void k_fold(const float* __restrict__ sw, const float* __restrict__ ssA,
                       float* __restrict__ swf){
  int c = threadIdx.x; if(c >= CH) return;
  float sc = ssA[c];
  swf[c*4+0] = sc*sw[c*3+0];
  swf[c*4+1] = sc*sw[c*3+1];
  swf[c*4+2] = sc*sw[c*3+2];
  swf[c*4+3] = ssA[CH+c];
}

// per-stage batched repack: 4 weight sets -> Wb4 slots [sel][tap][co][ci] bf16
__global__ void k_repack4(const float* __restrict__ w0, const float* __restrict__ w1,
                          const float* __restrict__ w2, const float* __restrict__ w3,
                          bf16* __restrict__ wb){
  int i = blockIdx.x*blockDim.x + threadIdx.x;
  if(i >= 4*WSZ) return;
  int sel = i/WSZ, r = i%WSZ;
  const float* w = (sel==0)?w0 : (sel==1)?w1 : (sel==2)?w2 : w3;
  int tap = r%9; int ci = (r/9)%CH; int co = r/(9*CH);
  wb[(size_t)sel*WSZ + tap*CH*CH + co*CH + ci] = __float2bfloat16(w[r]);
}

// ---------------- common MFMA epilogue: obuf[site][212] -> coalesced rows ----------------

static __device__ __forceinline__ void epi_store(f32x4 (&acc)[4][3], u16* obuf,
        u16* __restrict__ out, int b, int oy0, int ox0, int Ho, int Wo,
        int t, int co0, int l15, int q){
  __syncthreads();
#pragma unroll
  for(int mt=0;mt<4;mt++){
#pragma unroll
    for(int nt=0;nt<3;nt++){
      int co = co0 + nt*16 + l15;
#pragma unroll
      for(int r=0;r<4;r++){
        int site = mt*16 + q*4 + r;
        obuf[site*212 + co] = f2bu(acc[mt][nt][r]);
      }
    }
  }
  __syncthreads();
  for(int e=t; e<3072; e+=256){
    int r = e/384; int off = (e%384)*4;         // u16 offset within row [0,1536)
    int sx = off/CH, co = off%CH;
    ushort4 v = *(const ushort4*)&obuf[(r*8+sx)*212 + co];
    *(ushort4*)(out + ((size_t)(b*Ho+oy0+r)*Wo + ox0)*CH + off) = v;
  }
}

// ---------------- s1 3x3 conv: LDS-staged channels-last implicit GEMM ----------------
// block 256 thr (4 waves), 8x8 tile, all 192 co. M=64, N=192, K=9*192.
#define CIP 200
__global__ __launch_bounds__(256) void k_convm(const bf16* __restrict__ in,
        const bf16* __restrict__ wb, const u8* __restrict__ mk,
        bf16* __restrict__ out, int Ho, int Wo){
  __shared__ __align__(16) u16 tile[10*10*CIP];   // 40 KB; obuf aliased
  __shared__ int anyact;
  const int t = threadIdx.x;
  const int b = blockIdx.z;
  const int ox0 = blockIdx.x*8, oy0 = blockIdx.y*8;

  if(t == 0) anyact = 0;
  __syncthreads();
  if(t < 64){
    int r = t >> 3, c = t & 7;
    if(mk[(b*Ho + oy0 + r)*Wo + ox0 + c]) anyact = 1;
  }
  __syncthreads();
  if(!anyact) return;

  const u16* inp = (const u16*)in;
  const int gy0 = oy0 - 1, gx0 = ox0 - 1;
  // stage 10x10 window, 24 uint4 units per site
  for(int u=t; u<2400; u+=256){
    int y = u/240; int rem = u%240; int x = rem/24; int cu = rem%24;
    int gy = gy0 + y, gx = gx0 + x;
    uint4 v = {0u,0u,0u,0u};
    if(gy >= 0 && gy < Ho && gx >= 0 && gx < Wo)
      v = *(const uint4*)(inp + ((size_t)(b*Ho+gy)*Wo+gx)*CH + cu*8);
    *(uint4*)&tile[(y*10+x)*CIP + cu*8] = v;
  }
  __syncthreads();

  const int w = t >> 6;
  const int l = t & 63;
  const int l15 = l & 15, q = l >> 4;
  f32x4 acc[4][3];
#pragma unroll
  for(int mt=0;mt<4;mt++)
#pragma unroll
    for(int nt=0;nt<3;nt++) acc[mt][nt] = (f32x4){0.f,0.f,0.f,0.f};

  int sy[4], sx[4];
#pragma unroll
  for(int mt=0;mt<4;mt++){ int s = mt*16 + l15; sy[mt] = s>>3; sx[mt] = s&7; }
  const int co0 = w*48;

  for(int tap=0; tap<9; tap++){
    const int ky = tap/3, kx = tap%3;
    const u16* tb[4];
#pragma unroll
    for(int mt=0;mt<4;mt++)
      tb[mt] = &tile[((sy[mt]+ky)*10 + sx[mt]+kx)*CIP + q*8];
    const u16* wt0 = (const u16*)(wb + (size_t)tap*CH*CH);
#pragma unroll
    for(int c=0;c<6;c++){
      bf16x8 a[4], bb[3];
#pragma unroll
      for(int mt=0;mt<4;mt++) a[mt] = *(const bf16x8*)(tb[mt] + c*32);
#pragma unroll
      for(int nt=0;nt<3;nt++){
        int co = co0 + nt*16 + l15;
        bb[nt] = *(const bf16x8*)(wt0 + co*CH + c*32 + q*8);
      }
#pragma unroll
      for(int mt=0;mt<4;mt++)
#pragma unroll
        for(int nt=0;nt<3;nt++)
          acc[mt][nt] = __builtin_amdgcn_mfma_f32_16x16x32_bf16(a[mt], bb[nt], acc[mt][nt], 0, 0, 0);
    }
  }
  epi_store(acc, tile, (u16*)out, b, oy0, ox0, Ho, Wo, t, co0, l15, q);
}

// ---------------- s2 3x3 conv: direct-global A-frags (no input LDS) ----------------

__global__ __launch_bounds__(256) void k_convs2(const bf16* __restrict__ in,
        const bf16* __restrict__ wb, const u8* __restrict__ mk,
        bf16* __restrict__ out, int Ho, int Wo){
  __shared__ __align__(16) u16 obuf[64*212];
  __shared__ int anyact;
  const int t = threadIdx.x;
  const int b = blockIdx.z;
  const int ox0 = blockIdx.x*8, oy0 = blockIdx.y*8;
  const int Hi = Ho*2, Wi = Wo*2;

  if(t == 0) anyact = 0;
  __syncthreads();
  if(t < 64){
    int r = t >> 3, c = t & 7;
    if(mk[(b*Ho + oy0 + r)*Wo + ox0 + c]) anyact = 1;
  }
  __syncthreads();
  if(!anyact) return;

  const u16* inp = (const u16*)in;
  const int w = t >> 6;
  const int l = t & 63;
  const int l15 = l & 15, q = l >> 4;
  f32x4 acc[4][3];
#pragma unroll
  for(int mt=0;mt<4;mt++)
#pragma unroll
    for(int nt=0;nt<3;nt++) acc[mt][nt] = (f32x4){0.f,0.f,0.f,0.f};

  int gyb[4], gxb[4];
#pragma unroll
  for(int mt=0;mt<4;mt++){
    int s = mt*16 + l15;
    gyb[mt] = (oy0 + (s>>3))*2 - 1;
    gxb[mt] = (ox0 + (s&7))*2 - 1;
  }
  const int co0 = w*48;
  const bf16x8 zro = {0,0,0,0,0,0,0,0};

  for(int tap=0; tap<9; tap++){
    const int ky = tap/3, kx = tap%3;
    const u16* ap[4]; bool av[4];
#pragma unroll
    for(int mt=0;mt<4;mt++){
      int gy = gyb[mt] + ky, gx = gxb[mt] + kx;
      av[mt] = (gy >= 0 && gy < Hi && gx >= 0 && gx < Wi);
      ap[mt] = inp + ((size_t)(b*Hi+gy)*Wi+gx)*CH + q*8;
    }
    const u16* wt0 = (const u16*)(wb + (size_t)tap*CH*CH);
#pragma unroll
    for(int c=0;c<6;c++){
      bf16x8 a[4], bb[3];
#pragma unroll
      for(int mt=0;mt<4;mt++) a[mt] = av[mt] ? *(const bf16x8*)(ap[mt] + c*32) : zro;
#pragma unroll
      for(int nt=0;nt<3;nt++){
        int co = co0 + nt*16 + l15;
        bb[nt] = *(const bf16x8*)(wt0 + co*CH + c*32 + q*8);
      }
#pragma unroll
      for(int mt=0;mt<4;mt++)
#pragma unroll
        for(int nt=0;nt<3;nt++)
          acc[mt][nt] = __builtin_amdgcn_mfma_f32_16x16x32_bf16(a[mt], bb[nt], acc[mt][nt], 0, 0, 0);
    }
  }
  epi_store(acc, obuf, (u16*)out, b, oy0, ox0, Ho, Wo, t, co0, l15, q);
}

// ---------------- stage-0 (256->128 s2) with fused stem (BN folded into swf) ----------------
#define CIP2 104
__global__ __launch_bounds__(256) void k_conv0m(const float* __restrict__ im,
        const float* __restrict__ swf, const u8* __restrict__ m0,
        const bf16* __restrict__ wb, const u8* __restrict__ mk,
        bf16* __restrict__ out){
  __shared__ __align__(16) u16 tile[289*CIP2];   // 60112 B; obuf aliased
  __shared__ float rgbs[3][292];
  __shared__ u8 mts[292];
  __shared__ int anyact;
  const int t = threadIdx.x;
  const int b = blockIdx.z;
  const int ox0 = blockIdx.x*8, oy0 = blockIdx.y*8;

  if(t == 0) anyact = 0;
  __syncthreads();
  if(t < 64){
    int r = t >> 3, c = t & 7;
    if(mk[(b*128 + oy0 + r)*128 + ox0 + c]) anyact = 1;
  }
  __syncthreads();
  if(!anyact) return;

  const int gy0 = oy0*2 - 1, gx0 = ox0*2 - 1;
  for(int e=t; e<289; e+=256){
    int r = e/17, c = e%17;
    int gy = gy0 + r, gx = gx0 + c;
    float r_=0.f, g_=0.f, bl=0.f; u8 mv=0;
    if(gy >= 0 && gy < 256 && gx >= 0 && gx < 256){
      int pi = gy*256 + gx;
      mv = m0[b*65536 + pi];
      r_ = im[(size_t)(b*3+0)*65536 + pi];
      g_ = im[(size_t)(b*3+1)*65536 + pi];
      bl = im[(size_t)(b*3+2)*65536 + pi];
    }
    rgbs[0][e]=r_; rgbs[1][e]=g_; rgbs[2][e]=bl; mts[e]=mv;
  }

  const int w = t >> 6;
  const int l = t & 63;
  const int l15 = l & 15, q = l >> 4;
  f32x4 acc[4][3];
#pragma unroll
  for(int mt=0;mt<4;mt++)
#pragma unroll
    for(int nt=0;nt<3;nt++) acc[mt][nt] = (f32x4){0.f,0.f,0.f,0.f};

  int siy[4], six[4];
#pragma unroll
  for(int mt=0;mt<4;mt++){ int s = mt*16 + l15; siy[mt] = (s>>3)*2; six[mt] = (s&7)*2; }
  const int co0 = w*48;

  for(int h=0; h<2; h++){
    __syncthreads();
    // stem into LDS tile [site][ci_local] (pairs of channels, packed u32 writes)
    for(int e=t; e<289*48; e+=256){
      int site = e/48, cp = e%48;
      int ci = h*96 + cp*2;
      float4 w0 = *(const float4*)&swf[ci*4];
      float4 w1 = *(const float4*)&swf[(ci+1)*4];
      float r_ = rgbs[0][site], g_ = rgbs[1][site], b_ = rgbs[2][site];
      u8 mv = mts[site];
      float d0 = w0.x*r_ + w0.y*g_ + w0.z*b_ + w0.w;
      float d1 = w1.x*r_ + w1.y*g_ + w1.z*b_ + w1.w;
      u16 p0 = mv ? f2bu(fmaxf(d0, 0.f)) : (u16)0;
      u16 p1 = mv ? f2bu(fmaxf(d1, 0.f)) : (u16)0;
      *(u32*)&tile[site*CIP2 + cp*2] = (u32)p0 | ((u32)p1 << 16);
    }
    __syncthreads();
    for(int tap=0; tap<9; tap++){
      const int ky = tap/3, kx = tap%3;
      const u16* tb[4];
#pragma unroll
      for(int mt=0;mt<4;mt++)
        tb[mt] = &tile[((siy[mt]+ky)*17 + six[mt]+kx)*CIP2 + q*8];
      const u16* wt0 = (const u16*)(wb + (size_t)tap*CH*CH);
#pragma unroll
      for(int c=0;c<3;c++){
        bf16x8 a[4], bb[3];
#pragma unroll
        for(int mt=0;mt<4;mt++) a[mt] = *(const bf16x8*)(tb[mt] + c*32);
#pragma unroll
        for(int nt=0;nt<3;nt++){
          int co = co0 + nt*16 + l15;
          bb[nt] = *(const bf16x8*)(wt0 + co*CH + h*96 + c*32 + q*8);
        }
#pragma unroll
        for(int mt=0;mt<4;mt++)
#pragma unroll
          for(int nt=0;nt<3;nt++)
            acc[mt][nt] = __builtin_amdgcn_mfma_f32_16x16x32_bf16(a[mt], bb[nt], acc[mt][nt], 0, 0, 0);
      }
    }
  }
  epi_store(acc, tile, (u16*)out, b, oy0, ox0, 128, 128, t, co0, l15, q);
}

// ---------------- masked BN (channels-last) ----------------

// thread = channel; block covers a chunk of sites; coalesced 384B row reads
__global__ __launch_bounds__(192) void k_bnstats(const bf16* __restrict__ x,
        const u8* __restrict__ m, float* __restrict__ stats, int sites){
  int c = threadIdx.x;
  int nchunk = gridDim.x;
  int per = (sites + nchunk - 1)/nchunk;
  int s0 = blockIdx.x*per;
  int s1 = s0 + per; if(s1 > sites) s1 = sites;
  float s = 0.f, s2 = 0.f;
  for(int si = s0; si < s1; si++){
    if(m[si]){
      float v = bf2f(x[(size_t)si*CH + c]);
      s += v; s2 += v*v;
    }
  }
  atomicAdd(&stats[c], s);
  atomicAdd(&stats[CH + c], s2);
}

// finalize + self-zero stats for the next BN
__global__ void k_bnfinal(float* __restrict__ stats, const float* __restrict__ cnt,
                          const float* __restrict__ g, const float* __restrict__ bb,
                          float* __restrict__ ss){
  int c = threadIdx.x; if(c >= CH) return;
  float n = fmaxf(*cnt, 1.0f);
  float mean = stats[c]/n;
  float var = stats[CH + c]/n - mean*mean;
  var = fmaxf(var, 0.f);
  float rstd = rsqrtf(var + 1e-5f);
  float sc = g[c]*rstd;
  ss[c] = sc;
  ss[CH + c] = bb[c] - mean*sc;
  stats[c] = 0.f;
  stats[CH + c] = 0.f;
}

template<int RELU, int ADD>
__global__ void k_bnapply(const bf16* __restrict__ x, const u8* __restrict__ m,
                          const float* __restrict__ ss, const bf16* __restrict__ idn,
                          bf16* __restrict__ out, int sites){
  int i = blockIdx.x*blockDim.x + threadIdx.x;
  int total = sites*CH; if(i >= total) return;
  int c = i % CH; int si = i / CH;
  float v = bf2f(x[i])*ss[c] + ss[CH + c];
  v *= (float)m[si];
  if(ADD) v += bf2f(idn[i]);
  if(RELU) v = fmaxf(v, 0.f);
  out[i] = __float2bfloat16(v);
}

// final BN apply: channels-last in -> NCHW f32 out (x region of d_out)
__global__ void k_bnapply_out(const bf16* __restrict__ x, const u8* __restrict__ m,
                              const float* __restrict__ ss, float* __restrict__ out){
  int i = blockIdx.x*blockDim.x + threadIdx.x;
  if(i >= NB*CH*256) return;
  int p = i % 256; int c = (i/256) % CH; int b = i/(256*CH);
  int si = b*256 + p;
  float v = bf2f(x[(size_t)si*CH + c])*ss[c] + ss[CH + c];
  v *= (float)m[si];
  v = fmaxf(v, 0.f);
  out[i] = v;
}

// ---------------- final 1x1 conv at 16x16 (channels-last) ----------------

__global__ void k_final(const bf16* __restrict__ in, const float* __restrict__ w,
                        const u8* __restrict__ m4, bf16* __restrict__ out){
  int i = blockIdx.x*blockDim.x + threadIdx.x;
  if(i >= NB*256*CH) return;
  int co = i % CH; int si = i / CH;
  if(!m4[si]) return;  // garbage masked by bnapply_out
  float acc = 0.f;
  const bf16* ib = in + (size_t)si*CH;
  for(int ci=0; ci<CH; ci++)
    acc += w[co*CH + ci]*bf2f(ib[ci]);
  out[i] = __float2bfloat16(acc);
}

// ---------------- tail ----------------

__global__ void k_tail(const int* __restrict__ mask, float* __restrict__ out){
  int i = blockIdx.x*blockDim.x + threadIdx.x;
  if(i < 2048){
    out[393216 + i] = (float)mask[i];
  } else if(i < 4096){
    int j = i - 2048;
    out[395264 + j] = (float)(j & 255);
  }
}

// ---------------- host orchestration ----------------

extern "C" void kernel_launch(void* const* d_in, const int* in_sizes, int n_in,
                              void* d_out, int out_size, void* d_ws, size_t ws_size,
                              hipStream_t stream){
  const float* images = (const float*)d_in[0];
  const int*   maskI  = (const int*)d_in[1];
  const float* stem_w = (const float*)d_in[2];
  const float* stem_g = (const float*)d_in[3];
  const float* stem_b = (const float*)d_in[4];
  const float* dw1 = (const float*)d_in[5];
  const float* dg1 = (const float*)d_in[6];
  const float* db1 = (const float*)d_in[7];
  const float* dw2 = (const float*)d_in[8];
  const float* dg2 = (const float*)d_in[9];
  const float* db2 = (const float*)d_in[10];
  const float* rw1 = (const float*)d_in[11];
  const float* rg1 = (const float*)d_in[12];
  const float* rb1 = (const float*)d_in[13];
  const float* rw2 = (const float*)d_in[14];
  const float* rg2 = (const float*)d_in[15];
  const float* rb2 = (const float*)d_in[16];
  const float* final_w = (const float*)d_in[17];
  const float* final_g = (const float*)d_in[18];
  const float* final_b = (const float*)d_in[19];
  float* outF = (float*)d_out;

  char* wsp = (char*)d_ws;
  auto alloc = [&](size_t bytes)->char*{
    char* p = wsp; wsp += (bytes + 255) & ~(size_t)255; return p;
  };
  bf16* S0 = (bf16*)alloc((size_t)NB*CH*16384*2);
  bf16* S1 = (bf16*)alloc((size_t)NB*CH*16384*2);
  bf16* S2 = (bf16*)alloc((size_t)NB*CH*16384*2);
  int Hs[5] = {256,128,64,32,16};
  u8* M[5];
  for(int l=0;l<5;l++) M[l] = (u8*)alloc((size_t)NB*Hs[l]*Hs[l]);
  bf16*  Wb4 = (bf16*)alloc((size_t)4*WSZ*2);   // 2.65 MB, 4 slots per stage
  float* swf = (float*)alloc(CH*4*4);
  float* stats = (float*)alloc(2*CH*4);
  float* ss    = (float*)alloc(2*CH*4);
  float* ssA   = (float*)alloc(2*CH*4);
  float* cnts  = (float*)alloc(8*4);
  size_t need = (size_t)(wsp - (char*)d_ws);

  if(ws_size < need){
    k_fill<<<(393216+255)/256, 256, 0, stream>>>(outF, 393216, 777.0f);
    k_tail<<<16, 256, 0, stream>>>(maskI, outF);
    return;
  }

  // ---- mask pyramid + counts ----
  k_mask0<<<(NB*65536+255)/256, 256, 0, stream>>>(maskI, M[0]);
  for(int l=1;l<5;l++){
    int total = NB*Hs[l]*Hs[l];
    k_maskdown<<<(total+255)/256, 256, 0, stream>>>(M[l-1], M[l], Hs[l], Hs[l], Hs[l-1], Hs[l-1]);
  }
  k_zero<<<1, 32, 0, stream>>>(cnts, 8);
  for(int l=0;l<5;l++){
    int n = NB*Hs[l]*Hs[l];
    int blocks = (n + 256*64 - 1)/(256*64); if(blocks < 1) blocks = 1; if(blocks > 256) blocks = 256;
    k_count<<<blocks, 256, 0, stream>>>(M[l], n, cnts + l);
  }

  // ---- stem BN params + fold ----
  k_zero<<<2, 256, 0, stream>>>(stats, 2*CH);
  k_stemstats2<<<dim3(CH, 128), 256, 0, stream>>>(images, M[0], stem_w, stats);
  k_bnfinal<<<1, CH, 0, stream>>>(stats, cnts + 0, stem_g, stem_b, ssA);
  k_fold<<<1, CH, 0, stream>>>(stem_w, ssA, swf);

  // masked-BN helper (levels 1..4), channels-last bf16
  auto bn = [&](const bf16* x, int lvl, const float* g, const float* bb,
                int relu, const bf16* idn, bf16* outp){
    int sites = NB*Hs[lvl]*Hs[lvl];
    int nchunk = sites/256; if(nchunk < 1) nchunk = 1;
    k_bnstats<<<nchunk, 192, 0, stream>>>(x, M[lvl], stats, sites);
    k_bnfinal<<<1, CH, 0, stream>>>(stats, cnts + lvl, g, bb, ss);
    int total = sites*CH;
    int blocks = (total + 255)/256;
    if(idn)          k_bnapply<1,1><<<blocks, 256, 0, stream>>>(x, M[lvl], ss, idn, outp, sites);
    else if(relu)    k_bnapply<1,0><<<blocks, 256, 0, stream>>>(x, M[lvl], ss, nullptr, outp, sites);
    else             k_bnapply<0,0><<<blocks, 256, 0, stream>>>(x, M[lvl], ss, nullptr, outp, sites);
  };

  auto conv = [&](const bf16* inp, const bf16* wb, int Ho, int stride,
                  bf16* outp, const u8* mk){
    dim3 g(Ho/8, Ho/8, NB);
    if(stride == 1) k_convm<<<g, 256, 0, stream>>>(inp, wb, mk, outp, Ho, Ho);
    else            k_convs2<<<g, 256, 0, stream>>>(inp, wb, mk, outp, Ho, Ho);
  };

  // ---- 4 stages ----
  bf16* X = nullptr;
  for(int i=0;i<4;i++){
    int Ho = Hs[i+1];
    const u8* mk = M[i+1];
    bf16* A = S0;
    bf16* B = (i % 2 == 0) ? S1 : S2;
    bf16* C2 = (i == 0) ? S2 : X;

    // batch-repack this stage's 4 weight sets: slots {dw1, dw2, rw1, rw2}
    k_repack4<<<(4*WSZ+255)/256, 256, 0, stream>>>(
        dw1 + (size_t)i*WSZ, dw2 + (size_t)i*WSZ,
        rw1 + (size_t)i*WSZ, rw2 + (size_t)i*WSZ, Wb4);

    if(i == 0){
      dim3 g(16, 16, NB);
      k_conv0m<<<g, 256, 0, stream>>>(images, swf, M[0], Wb4 + 0*WSZ, M[1], A);
    } else {
      conv(X, Wb4 + 0*WSZ, Ho, 2, A, mk);
    }
    bn(A, i+1, dg1 + i*CH, db1 + i*CH, 1, nullptr, A);
    conv(A, Wb4 + 1*WSZ, Ho, 1, B, mk);
    bn(B, i+1, dg2 + i*CH, db2 + i*CH, 0, nullptr, B);
    conv(B, Wb4 + 2*WSZ, Ho, 1, A, mk);
    bn(A, i+1, rg1 + i*CH, rb1 + i*CH, 1, nullptr, A);
    conv(A, Wb4 + 3*WSZ, Ho, 1, C2, mk);
    bn(C2, i+1, rg2 + i*CH, rb2 + i*CH, 1, B, B);  // relu(bn*m + idn) -> B
    X = B;
  }

  // ---- final 1x1 + BN + ReLU -> d_out (f32 NCHW) ----
  k_final<<<(NB*256*CH + 255)/256, 256, 0, stream>>>(X, final_w, M[4], S0);
  {
    int sites = NB*256;
    k_bnstats<<<sites/256, 192, 0, stream>>>(S0, M[4], stats, sites);
    k_bnfinal<<<1, CH, 0, stream>>>(stats, cnts + 4, final_g, final_b, ss);
    k_bnapply_out<<<(NB*CH*256 + 255)/256, 256, 0, stream>>>(S0, M[4], ss, outF);
  }

  // ---- tail ----
  k_tail<<<16, 256, 0, stream>>>(maskI, outF);
}

// Round 10
// 1791.556 us; speedup vs baseline: 2.1023x; 2.1023x over previous
//
#include <hip/hip_runtime.h>
#include <hip/hip_bf16.h>

typedef __hip_bfloat16 bf16;
typedef unsigned short u16;
typedef unsigned int u32;
typedef unsigned char u8;
typedef __attribute__((ext_vector_type(8))) short bf16x8;
typedef __attribute__((ext_vector_type(4))) float f32x4;

#define NB 8
#define CH 192
#define WSZ (CH*CH*9)

// Activations channels-last: A[b][y][x][c], bf16. Convs write RAW outputs and
// accumulate masked BN stats; the consumer applies the affine on read.

static __device__ __forceinline__ float bf2f(bf16 v){ return __bfloat162float(v); }
static __device__ __forceinline__ u16 f2bu(float f){
  union { bf16 h; u16 u; } cv; cv.h = __float2bfloat16(f); return cv.u;
}

// ---------------- utility kernels ----------------

__global__ void k_zero(float* p, int n){
  int i = blockIdx.x*blockDim.x + threadIdx.x;
  if(i < n) p[i] = 0.f;
}

__global__ void k_fill(float* p, int n, float v){
  int i = blockIdx.x*blockDim.x + threadIdx.x;
  if(i < n) p[i] = v;
}

__global__ void k_mask0(const int* __restrict__ mask, u8* __restrict__ m0){
  int i = blockIdx.x*blockDim.x + threadIdx.x;
  if(i >= NB*65536) return;
  int b = i >> 16; int p = i & 65535;
  int y = p >> 8, x = p & 255;
  int patch = (y >> 4)*16 + (x >> 4);
  m0[i] = (u8)(1 - mask[b*256 + patch]);
}

__global__ void k_maskdown(const u8* __restrict__ mi, u8* __restrict__ mo,
                           int Ho, int Wo, int Hi, int Wi){
  int i = blockIdx.x*blockDim.x + threadIdx.x;
  int total = NB*Ho*Wo; if(i >= total) return;
  int b = i/(Ho*Wo); int p = i%(Ho*Wo);
  int oy = p/Wo, ox = p%Wo;
  u8 v = 0;
  for(int ky=0; ky<3; ky++){
    int iy = oy*2 + ky - 1; if(iy < 0 || iy >= Hi) continue;
    for(int kx=0; kx<3; kx++){
      int ix = ox*2 + kx - 1; if(ix < 0 || ix >= Wi) continue;
      u8 t = mi[(b*Hi + iy)*Wi + ix]; if(t > v) v = t;
    }
  }
  mo[i] = v;
}

__global__ void k_count(const u8* __restrict__ m, int n, float* cnt){
  int i = blockIdx.x*blockDim.x + threadIdx.x;
  int stride = gridDim.x*blockDim.x;
  int local = 0;
  for(int j=i; j<n; j+=stride) local += m[j];
  for(int o=32; o>0; o>>=1) local += __shfl_down(local, o, 64);
  if((threadIdx.x & 63) == 0 && local) atomicAdd(cnt, (float)local);
}

// ---------------- stem BN stats (images NCHW f32) -> statsF ----------------

__global__ __launch_bounds__(256) void k_stemstats2(const float* __restrict__ im,
        const u8* __restrict__ m0, const float* __restrict__ sw,
        float* __restrict__ stats){
  int c = blockIdx.x;
  int chunk = blockIdx.y;
  float w0 = sw[c*3+0], w1 = sw[c*3+1], w2 = sw[c*3+2];
  float s = 0.f, s2 = 0.f;
  int start = chunk*4096;
  for(int j = start + threadIdx.x; j < start + 4096; j += 256){
    if(m0[j]){
      int b = j >> 16, p = j & 65535;
      float d = w0*im[(size_t)(b*3+0)*65536 + p]
              + w1*im[(size_t)(b*3+1)*65536 + p]
              + w2*im[(size_t)(b*3+2)*65536 + p];
      s += d; s2 += d*d;
    }
  }
  for(int o=32; o>0; o>>=1){ s += __shfl_down(s, o, 64); s2 += __shfl_down(s2, o, 64); }
  __shared__ float sh[8];
  int w = threadIdx.x >> 6;
  if((threadIdx.x & 63) == 0){ sh[w] = s; sh[4+w] = s2; }
  __syncthreads();
  if(threadIdx.x == 0){
    float ts = 0.f, t2 = 0.f;
    for(int k=0;k<4;k++){ ts += sh[k]; t2 += sh[4+k]; }
    atomicAdd(&stats[c], ts);
    atomicAdd(&stats[CH + c], t2);
  }
}

__global__ void k_fold(const float* __restrict__ sw, const float* __restrict__ ssA,
                       float* __restrict__ swf){
  int c = threadIdx.x; if(c >= CH) return;
  float sc = ssA[c];
  swf[c*4+0] = sc*sw[c*3+0];
  swf[c*4+1] = sc*sw[c*3+1];
  swf[c*4+2] = sc*sw[c*3+2];
  swf[c*4+3] = ssA[CH+c];
}

// per-stage batched repack: 4 weight sets -> Wb4 slots [sel][tap][co][ci] bf16
__global__ void k_repack4(const float* __restrict__ w0, const float* __restrict__ w1,
                          const float* __restrict__ w2, const float* __restrict__ w3,
                          bf16* __restrict__ wb){
  int i = blockIdx.x*blockDim.x + threadIdx.x;
  if(i >= 4*WSZ) return;
  int sel = i/WSZ, r = i%WSZ;
  const float* w = (sel==0)?w0 : (sel==1)?w1 : (sel==2)?w2 : w3;
  int tap = r%9; int ci = (r/9)%CH; int co = r/(9*CH);
  wb[(size_t)sel*WSZ + tap*CH*CH + co*CH + ci] = __float2bfloat16(w[r]);
}

// ---------------- BN finalize kernels (self-zeroing) ----------------

// single 384-float stats buffer (stem, final 1x1)
__global__ void k_bnfinalA(float* __restrict__ stats, const float* __restrict__ cnt,
                           const float* __restrict__ g, const float* __restrict__ bb,
                           float* __restrict__ ss){
  int c = threadIdx.x; if(c >= CH) return;
  float n = fmaxf(*cnt, 1.0f);
  float mean = stats[c]/n;
  float var = stats[CH + c]/n - mean*mean;
  var = fmaxf(var, 0.f);
  float rstd = rsqrtf(var + 1e-5f);
  float sc = g[c]*rstd;
  ss[c] = sc;
  ss[CH + c] = bb[c] - mean*sc;
  stats[c] = 0.f; stats[CH + c] = 0.f;
}

// 8-slot per-batch stats buffer (conv-fused stats)
__global__ void k_bnfinal8(float* __restrict__ statsB, const float* __restrict__ cnt,
                           const float* __restrict__ g, const float* __restrict__ bb,
                           float* __restrict__ ss){
  int c = threadIdx.x; if(c >= CH) return;
  float s = 0.f, s2 = 0.f;
  for(int b=0;b<NB;b++){
    s  += statsB[b*384 + c];
    s2 += statsB[b*384 + 192 + c];
    statsB[b*384 + c] = 0.f;
    statsB[b*384 + 192 + c] = 0.f;
  }
  float n = fmaxf(*cnt, 1.0f);
  float mean = s/n;
  float var = s2/n - mean*mean;
  var = fmaxf(var, 0.f);
  float rstd = rsqrtf(var + 1e-5f);
  float sc = g[c]*rstd;
  ss[c] = sc;
  ss[CH + c] = bb[c] - mean*sc;
}

// ---------------- shared conv epilogues ----------------

// masked per-channel sum/sumsq of the f32 tile, atomicAdd to per-batch slot
static __device__ __forceinline__ void epi_stats(f32x4 (&acc)[4][3], const u8* sm,
        float* __restrict__ statsB, int b, int co0, int l15, int q, int lane){
  float s[3], s2[3];
#pragma unroll
  for(int nt=0;nt<3;nt++){ s[nt]=0.f; s2[nt]=0.f; }
#pragma unroll
  for(int mt=0;mt<4;mt++){
#pragma unroll
    for(int r=0;r<4;r++){
      int site = mt*16 + q*4 + r;
      float mv = (float)sm[site];
#pragma unroll
      for(int nt=0;nt<3;nt++){
        float v = acc[mt][nt][r]*mv;
        s[nt] += v; s2[nt] += v*v;
      }
    }
  }
#pragma unroll
  for(int nt=0;nt<3;nt++){
    s[nt]  += __shfl_down(s[nt], 32, 64);  s[nt]  += __shfl_down(s[nt], 16, 64);
    s2[nt] += __shfl_down(s2[nt], 32, 64); s2[nt] += __shfl_down(s2[nt], 16, 64);
  }
  if(lane < 16){
#pragma unroll
    for(int nt=0;nt<3;nt++){
      int co = co0 + nt*16 + l15;
      atomicAdd(&statsB[b*384 + co], s[nt]);
      atomicAdd(&statsB[b*384 + 192 + co], s2[nt]);
    }
  }
}

static __device__ __forceinline__ void epi_store(f32x4 (&acc)[4][3], u16* obuf,
        u16* __restrict__ out, int b, int oy0, int ox0, int Ho, int Wo,
        int t, int co0, int l15, int q){
  __syncthreads();
#pragma unroll
  for(int mt=0;mt<4;mt++){
#pragma unroll
    for(int nt=0;nt<3;nt++){
      int co = co0 + nt*16 + l15;
#pragma unroll
      for(int r=0;r<4;r++){
        int site = mt*16 + q*4 + r;
        obuf[site*212 + co] = f2bu(acc[mt][nt][r]);
      }
    }
  }
  __syncthreads();
  for(int e=t; e<3072; e+=256){
    int r = e/384; int off = (e%384)*4;
    int sx = off/CH, co = off%CH;
    ushort4 v = *(const ushort4*)&obuf[(r*8+sx)*212 + co];
    *(ushort4*)(out + ((size_t)(b*Ho+oy0+r)*Wo + ox0)*CH + off) = v;
  }
}

// ---------------- s1 3x3 conv: LDS-staged, pre-affine BN on staging ----------------
#define CIP 200
template<int RELU>
__global__ __launch_bounds__(256) void k_convm(const bf16* __restrict__ in,
        const bf16* __restrict__ wb, const u8* __restrict__ mk,
        bf16* __restrict__ out, int Ho, int Wo,
        const float* __restrict__ ssp, float* __restrict__ statsB){
  __shared__ __align__(16) u16 tile[10*10*CIP];   // 40 KB; obuf aliased
  __shared__ u8 sm[64];
  __shared__ u8 wmk[100];
  __shared__ int anyact;
  const int t = threadIdx.x;
  const int b = blockIdx.z;
  const int ox0 = blockIdx.x*8, oy0 = blockIdx.y*8;
  const int gy0 = oy0 - 1, gx0 = ox0 - 1;

  if(t == 0) anyact = 0;
  __syncthreads();
  if(t < 64){
    int r = t >> 3, c = t & 7;
    u8 mv = mk[(b*Ho + oy0 + r)*Wo + ox0 + c];
    sm[t] = mv;
    if(mv) anyact = 1;
  }
  if(t >= 64 && t < 164){
    int e = t - 64;
    int y = e/10, x = e%10;
    int gy = gy0 + y, gx = gx0 + x;
    u8 mv = 0;
    if(gy >= 0 && gy < Ho && gx >= 0 && gx < Wo) mv = mk[(b*Ho+gy)*Wo+gx];
    wmk[e] = mv;
  }
  __syncthreads();
  if(!anyact) return;

  const u16* inp = (const u16*)in;
  for(int u=t; u<2400; u+=256){
    int y = u/240; int rem = u%240; int x = rem/24; int cu = rem%24;
    int gy = gy0 + y, gx = gx0 + x;
    uint4 v = {0u,0u,0u,0u};
    if(wmk[y*10+x] && gy >= 0 && gy < Ho && gx >= 0 && gx < Wo){
      v = *(const uint4*)(inp + ((size_t)(b*Ho+gy)*Wo+gx)*CH + cu*8);
      // apply BN affine of the producing layer (+mask handled by wmk, +relu opt)
      int c0 = cu*8;
      float4 sca = *(const float4*)&ssp[c0];
      float4 scb = *(const float4*)&ssp[c0+4];
      float4 sha = *(const float4*)&ssp[CH+c0];
      float4 shb = *(const float4*)&ssp[CH+c0+4];
      u16* pv = (u16*)&v;
      float scv[8] = {sca.x,sca.y,sca.z,sca.w, scb.x,scb.y,scb.z,scb.w};
      float shv[8] = {sha.x,sha.y,sha.z,sha.w, shb.x,shb.y,shb.z,shb.w};
#pragma unroll
      for(int j=0;j<8;j++){
        union { bf16 h; u16 u; } cv2; cv2.u = pv[j];
        float f = __bfloat162float(cv2.h)*scv[j] + shv[j];
        if(RELU) f = fmaxf(f, 0.f);
        pv[j] = f2bu(f);
      }
    }
    *(uint4*)&tile[(y*10+x)*CIP + cu*8] = v;
  }
  __syncthreads();

  const int w = t >> 6;
  const int l = t & 63;
  const int l15 = l & 15, q = l >> 4;
  f32x4 acc[4][3];
#pragma unroll
  for(int mt=0;mt<4;mt++)
#pragma unroll
    for(int nt=0;nt<3;nt++) acc[mt][nt] = (f32x4){0.f,0.f,0.f,0.f};

  int sy[4], sx[4];
#pragma unroll
  for(int mt=0;mt<4;mt++){ int s = mt*16 + l15; sy[mt] = s>>3; sx[mt] = s&7; }
  const int co0 = w*48;

  for(int tap=0; tap<9; tap++){
    const int ky = tap/3, kx = tap%3;
    const u16* tb[4];
#pragma unroll
    for(int mt=0;mt<4;mt++)
      tb[mt] = &tile[((sy[mt]+ky)*10 + sx[mt]+kx)*CIP + q*8];
    const u16* wt0 = (const u16*)(wb + (size_t)tap*CH*CH);
#pragma unroll
    for(int c=0;c<6;c++){
      bf16x8 a[4], bb[3];
#pragma unroll
      for(int mt=0;mt<4;mt++) a[mt] = *(const bf16x8*)(tb[mt] + c*32);
#pragma unroll
      for(int nt=0;nt<3;nt++){
        int co = co0 + nt*16 + l15;
        bb[nt] = *(const bf16x8*)(wt0 + co*CH + c*32 + q*8);
      }
#pragma unroll
      for(int mt=0;mt<4;mt++)
#pragma unroll
        for(int nt=0;nt<3;nt++)
          acc[mt][nt] = __builtin_amdgcn_mfma_f32_16x16x32_bf16(a[mt], bb[nt], acc[mt][nt], 0, 0, 0);
    }
  }
  epi_stats(acc, sm, statsB, b, co0, l15, q, l);
  epi_store(acc, tile, (u16*)out, b, oy0, ox0, Ho, Wo, t, co0, l15, q);
}

// ---------------- s2 3x3 conv: direct-global A-frags (input pre-masked X) ----------------

__global__ __launch_bounds__(256) void k_convs2(const bf16* __restrict__ in,
        const bf16* __restrict__ wb, const u8* __restrict__ mk,
        bf16* __restrict__ out, int Ho, int Wo, float* __restrict__ statsB){
  __shared__ __align__(16) u16 obuf[64*212];
  __shared__ u8 sm[64];
  __shared__ int anyact;
  const int t = threadIdx.x;
  const int b = blockIdx.z;
  const int ox0 = blockIdx.x*8, oy0 = blockIdx.y*8;
  const int Hi = Ho*2, Wi = Wo*2;

  if(t == 0) anyact = 0;
  __syncthreads();
  if(t < 64){
    int r = t >> 3, c = t & 7;
    u8 mv = mk[(b*Ho + oy0 + r)*Wo + ox0 + c];
    sm[t] = mv;
    if(mv) anyact = 1;
  }
  __syncthreads();
  if(!anyact) return;

  const u16* inp = (const u16*)in;
  const int w = t >> 6;
  const int l = t & 63;
  const int l15 = l & 15, q = l >> 4;
  f32x4 acc[4][3];
#pragma unroll
  for(int mt=0;mt<4;mt++)
#pragma unroll
    for(int nt=0;nt<3;nt++) acc[mt][nt] = (f32x4){0.f,0.f,0.f,0.f};

  int gyb[4], gxb[4];
#pragma unroll
  for(int mt=0;mt<4;mt++){
    int s = mt*16 + l15;
    gyb[mt] = (oy0 + (s>>3))*2 - 1;
    gxb[mt] = (ox0 + (s&7))*2 - 1;
  }
  const int co0 = w*48;
  const bf16x8 zro = {0,0,0,0,0,0,0,0};

  for(int tap=0; tap<9; tap++){
    const int ky = tap/3, kx = tap%3;
    const u16* ap[4]; bool av[4];
#pragma unroll
    for(int mt=0;mt<4;mt++){
      int gy = gyb[mt] + ky, gx = gxb[mt] + kx;
      av[mt] = (gy >= 0 && gy < Hi && gx >= 0 && gx < Wi);
      ap[mt] = inp + ((size_t)(b*Hi+gy)*Wi+gx)*CH + q*8;
    }
    const u16* wt0 = (const u16*)(wb + (size_t)tap*CH*CH);
#pragma unroll
    for(int c=0;c<6;c++){
      bf16x8 a[4], bb[3];
#pragma unroll
      for(int mt=0;mt<4;mt++) a[mt] = av[mt] ? *(const bf16x8*)(ap[mt] + c*32) : zro;
#pragma unroll
      for(int nt=0;nt<3;nt++){
        int co = co0 + nt*16 + l15;
        bb[nt] = *(const bf16x8*)(wt0 + co*CH + c*32 + q*8);
      }
#pragma unroll
      for(int mt=0;mt<4;mt++)
#pragma unroll
        for(int nt=0;nt<3;nt++)
          acc[mt][nt] = __builtin_amdgcn_mfma_f32_16x16x32_bf16(a[mt], bb[nt], acc[mt][nt], 0, 0, 0);
    }
  }
  epi_stats(acc, sm, statsB, b, co0, l15, q, l);
  epi_store(acc, obuf, (u16*)out, b, oy0, ox0, Ho, Wo, t, co0, l15, q);
}

// ---------------- stage-0 (256->128 s2) with fused stem ----------------
#define CIP2 104
__global__ __launch_bounds__(256) void k_conv0m(const float* __restrict__ im,
        const float* __restrict__ swf, const u8* __restrict__ m0,
        const bf16* __restrict__ wb, const u8* __restrict__ mk,
        bf16* __restrict__ out, float* __restrict__ statsB){
  __shared__ __align__(16) u16 tile[289*CIP2];   // 60112 B; obuf aliased
  __shared__ float rgbs[3][292];
  __shared__ u8 mts[292];
  __shared__ u8 sm[64];
  __shared__ int anyact;
  const int t = threadIdx.x;
  const int b = blockIdx.z;
  const int ox0 = blockIdx.x*8, oy0 = blockIdx.y*8;

  if(t == 0) anyact = 0;
  __syncthreads();
  if(t < 64){
    int r = t >> 3, c = t & 7;
    u8 mv = mk[(b*128 + oy0 + r)*128 + ox0 + c];
    sm[t] = mv;
    if(mv) anyact = 1;
  }
  __syncthreads();
  if(!anyact) return;

  const int gy0 = oy0*2 - 1, gx0 = ox0*2 - 1;
  for(int e=t; e<289; e+=256){
    int r = e/17, c = e%17;
    int gy = gy0 + r, gx = gx0 + c;
    float r_=0.f, g_=0.f, bl=0.f; u8 mv=0;
    if(gy >= 0 && gy < 256 && gx >= 0 && gx < 256){
      int pi = gy*256 + gx;
      mv = m0[b*65536 + pi];
      r_ = im[(size_t)(b*3+0)*65536 + pi];
      g_ = im[(size_t)(b*3+1)*65536 + pi];
      bl = im[(size_t)(b*3+2)*65536 + pi];
    }
    rgbs[0][e]=r_; rgbs[1][e]=g_; rgbs[2][e]=bl; mts[e]=mv;
  }

  const int w = t >> 6;
  const int l = t & 63;
  const int l15 = l & 15, q = l >> 4;
  f32x4 acc[4][3];
#pragma unroll
  for(int mt=0;mt<4;mt++)
#pragma unroll
    for(int nt=0;nt<3;nt++) acc[mt][nt] = (f32x4){0.f,0.f,0.f,0.f};

  int siy[4], six[4];
#pragma unroll
  for(int mt=0;mt<4;mt++){ int s = mt*16 + l15; siy[mt] = (s>>3)*2; six[mt] = (s&7)*2; }
  const int co0 = w*48;

  for(int h=0; h<2; h++){
    __syncthreads();
    for(int e=t; e<289*48; e+=256){
      int site = e/48, cp = e%48;
      int ci = h*96 + cp*2;
      float4 w0 = *(const float4*)&swf[ci*4];
      float4 w1 = *(const float4*)&swf[(ci+1)*4];
      float r_ = rgbs[0][site], g_ = rgbs[1][site], b_ = rgbs[2][site];
      u8 mv = mts[site];
      float d0 = w0.x*r_ + w0.y*g_ + w0.z*b_ + w0.w;
      float d1 = w1.x*r_ + w1.y*g_ + w1.z*b_ + w1.w;
      u16 p0 = mv ? f2bu(fmaxf(d0, 0.f)) : (u16)0;
      u16 p1 = mv ? f2bu(fmaxf(d1, 0.f)) : (u16)0;
      *(u32*)&tile[site*CIP2 + cp*2] = (u32)p0 | ((u32)p1 << 16);
    }
    __syncthreads();
    for(int tap=0; tap<9; tap++){
      const int ky = tap/3, kx = tap%3;
      const u16* tb[4];
#pragma unroll
      for(int mt=0;mt<4;mt++)
        tb[mt] = &tile[((siy[mt]+ky)*17 + six[mt]+kx)*CIP2 + q*8];
      const u16* wt0 = (const u16*)(wb + (size_t)tap*CH*CH);
#pragma unroll
      for(int c=0;c<3;c++){
        bf16x8 a[4], bb[3];
#pragma unroll
        for(int mt=0;mt<4;mt++) a[mt] = *(const bf16x8*)(tb[mt] + c*32);
#pragma unroll
        for(int nt=0;nt<3;nt++){
          int co = co0 + nt*16 + l15;
          bb[nt] = *(const bf16x8*)(wt0 + co*CH + h*96 + c*32 + q*8);
        }
#pragma unroll
        for(int mt=0;mt<4;mt++)
#pragma unroll
          for(int nt=0;nt<3;nt++)
            acc[mt][nt] = __builtin_amdgcn_mfma_f32_16x16x32_bf16(a[mt], bb[nt], acc[mt][nt], 0, 0, 0);
      }
    }
  }
  epi_stats(acc, sm, statsB, b, co0, l15, q, l);
  epi_store(acc, tile, (u16*)out, b, oy0, ox0, 128, 128, t, co0, l15, q);
}

// ---------------- residual combine: X = relu(aff4(D)*m + aff2(B)*m) ----------------

__global__ void k_resid(const bf16* __restrict__ xD, const bf16* __restrict__ xB,
                        const u8* __restrict__ m, const float* __restrict__ ssD,
                        const float* __restrict__ ssB, bf16* __restrict__ out, int sites){
  int i = blockIdx.x*blockDim.x + threadIdx.x;
  int total = sites*CH; if(i >= total) return;
  int c = i % CH; int si = i / CH;
  float mv = (float)m[si];
  float v = (bf2f(xD[i])*ssD[c] + ssD[CH+c])*mv;
  float u = (bf2f(xB[i])*ssB[c] + ssB[CH+c])*mv;
  out[i] = __float2bfloat16(fmaxf(v + u, 0.f));
}

// ---------------- final 1x1 conv at 16x16 + standalone stats ----------------

__global__ void k_final(const bf16* __restrict__ in, const float* __restrict__ w,
                        const u8* __restrict__ m4, bf16* __restrict__ out){
  int i = blockIdx.x*blockDim.x + threadIdx.x;
  if(i >= NB*256*CH) return;
  int co = i % CH; int si = i / CH;
  if(!m4[si]) return;
  float acc = 0.f;
  const bf16* ib = in + (size_t)si*CH;
  for(int ci=0; ci<CH; ci++)
    acc += w[co*CH + ci]*bf2f(ib[ci]);
  out[i] = __float2bfloat16(acc);
}

__global__ __launch_bounds__(192) void k_bnstatsF(const bf16* __restrict__ x,
        const u8* __restrict__ m, float* __restrict__ stats, int sites){
  int c = threadIdx.x;
  float s = 0.f, s2 = 0.f;
  for(int si = blockIdx.x; si < sites; si += gridDim.x){
    if(m[si]){
      float v = bf2f(x[(size_t)si*CH + c]);
      s += v; s2 += v*v;
    }
  }
  atomicAdd(&stats[c], s);
  atomicAdd(&stats[CH + c], s2);
}

__global__ void k_bnapply_out(const bf16* __restrict__ x, const u8* __restrict__ m,
                              const float* __restrict__ ss, float* __restrict__ out){
  int i = blockIdx.x*blockDim.x + threadIdx.x;
  if(i >= NB*CH*256) return;
  int p = i % 256; int c = (i/256) % CH; int b = i/(256*CH);
  int si = b*256 + p;
  float v = bf2f(x[(size_t)si*CH + c])*ss[c] + ss[CH + c];
  v *= (float)m[si];
  v = fmaxf(v, 0.f);
  out[i] = v;
}

// ---------------- tail ----------------

__global__ void k_tail(const int* __restrict__ mask, float* __restrict__ out){
  int i = blockIdx.x*blockDim.x + threadIdx.x;
  if(i < 2048){
    out[393216 + i] = (float)mask[i];
  } else if(i < 4096){
    int j = i - 2048;
    out[395264 + j] = (float)(j & 255);
  }
}

// ---------------- host orchestration ----------------

extern "C" void kernel_launch(void* const* d_in, const int* in_sizes, int n_in,
                              void* d_out, int out_size, void* d_ws, size_t ws_size,
                              hipStream_t stream){
  const float* images = (const float*)d_in[0];
  const int*   maskI  = (const int*)d_in[1];
  const float* stem_w = (const float*)d_in[2];
  const float* stem_g = (const float*)d_in[3];
  const float* stem_b = (const float*)d_in[4];
  const float* dw1 = (const float*)d_in[5];
  const float* dg1 = (const float*)d_in[6];
  const float* db1 = (const float*)d_in[7];
  const float* dw2 = (const float*)d_in[8];
  const float* dg2 = (const float*)d_in[9];
  const float* db2 = (const float*)d_in[10];
  const float* rw1 = (const float*)d_in[11];
  const float* rg1 = (const float*)d_in[12];
  const float* rb1 = (const float*)d_in[13];
  const float* rw2 = (const float*)d_in[14];
  const float* rg2 = (const float*)d_in[15];
  const float* rb2 = (const float*)d_in[16];
  const float* final_w = (const float*)d_in[17];
  const float* final_g = (const float*)d_in[18];
  const float* final_b = (const float*)d_in[19];
  float* outF = (float*)d_out;

  char* wsp = (char*)d_ws;
  auto alloc = [&](size_t bytes)->char*{
    char* p = wsp; wsp += (bytes + 255) & ~(size_t)255; return p;
  };
  bf16* S0 = (bf16*)alloc((size_t)NB*CH*16384*2);
  bf16* S1 = (bf16*)alloc((size_t)NB*CH*16384*2);
  bf16* S2 = (bf16*)alloc((size_t)NB*CH*16384*2);
  int Hs[5] = {256,128,64,32,16};
  u8* M[5];
  for(int l=0;l<5;l++) M[l] = (u8*)alloc((size_t)NB*Hs[l]*Hs[l]);
  bf16*  Wb4 = (bf16*)alloc((size_t)4*WSZ*2);
  float* swf = (float*)alloc(CH*4*4);
  float* statsB = (float*)alloc(NB*384*4);   // per-batch conv-fused stats
  float* statsF = (float*)alloc(384*4);      // stem + final 1x1 stats
  float* ssS[4];
  for(int k=0;k<4;k++) ssS[k] = (float*)alloc(2*CH*4);
  float* ssA   = (float*)alloc(2*CH*4);
  float* cnts  = (float*)alloc(8*4);
  size_t need = (size_t)(wsp - (char*)d_ws);

  if(ws_size < need){
    k_fill<<<(393216+255)/256, 256, 0, stream>>>(outF, 393216, 777.0f);
    k_tail<<<16, 256, 0, stream>>>(maskI, outF);
    return;
  }

  // ---- zero stats buffers (ws is poisoned each call) ----
  k_zero<<<((NB*384+384)+255)/256, 256, 0, stream>>>(statsB, NB*384 + 384);

  // ---- mask pyramid + counts ----
  k_mask0<<<(NB*65536+255)/256, 256, 0, stream>>>(maskI, M[0]);
  for(int l=1;l<5;l++){
    int total = NB*Hs[l]*Hs[l];
    k_maskdown<<<(total+255)/256, 256, 0, stream>>>(M[l-1], M[l], Hs[l], Hs[l], Hs[l-1], Hs[l-1]);
  }
  k_zero<<<1, 32, 0, stream>>>(cnts, 8);
  for(int l=0;l<5;l++){
    int n = NB*Hs[l]*Hs[l];
    int blocks = (n + 256*64 - 1)/(256*64); if(blocks < 1) blocks = 1; if(blocks > 256) blocks = 256;
    k_count<<<blocks, 256, 0, stream>>>(M[l], n, cnts + l);
  }

  // ---- stem BN params + fold ----
  k_stemstats2<<<dim3(CH, 128), 256, 0, stream>>>(images, M[0], stem_w, statsF);
  k_bnfinalA<<<1, CH, 0, stream>>>(statsF, cnts + 0, stem_g, stem_b, ssA);
  k_fold<<<1, CH, 0, stream>>>(stem_w, ssA, swf);

  // ---- 4 stages: conv(+stats) -> bnfinal8 -> conv(pre-affine) ... -> resid ----
  bf16* X = nullptr;
  for(int i=0;i<4;i++){
    int Ho = Hs[i+1];
    int sites = NB*Ho*Ho;
    const u8* mk = M[i+1];
    bf16* A = S0;
    bf16* B = (i % 2 == 0) ? S1 : S2;
    bf16* C2 = (i == 0) ? S2 : X;
    dim3 g(Ho/8, Ho/8, NB);

    k_repack4<<<(4*WSZ+255)/256, 256, 0, stream>>>(
        dw1 + (size_t)i*WSZ, dw2 + (size_t)i*WSZ,
        rw1 + (size_t)i*WSZ, rw2 + (size_t)i*WSZ, Wb4);

    if(i == 0){
      dim3 g0(16, 16, NB);
      k_conv0m<<<g0, 256, 0, stream>>>(images, swf, M[0], Wb4 + 0*WSZ, M[1], A, statsB);
    } else {
      k_convs2<<<g, 256, 0, stream>>>(X, Wb4 + 0*WSZ, mk, A, Ho, Ho, statsB);
    }
    k_bnfinal8<<<1, CH, 0, stream>>>(statsB, cnts + i+1, dg1 + i*CH, db1 + i*CH, ssS[0]);

    k_convm<1><<<g, 256, 0, stream>>>(A, Wb4 + 1*WSZ, mk, B, Ho, Ho, ssS[0], statsB);
    k_bnfinal8<<<1, CH, 0, stream>>>(statsB, cnts + i+1, dg2 + i*CH, db2 + i*CH, ssS[1]);

    k_convm<0><<<g, 256, 0, stream>>>(B, Wb4 + 2*WSZ, mk, A, Ho, Ho, ssS[1], statsB);
    k_bnfinal8<<<1, CH, 0, stream>>>(statsB, cnts + i+1, rg1 + i*CH, rb1 + i*CH, ssS[2]);

    k_convm<1><<<g, 256, 0, stream>>>(A, Wb4 + 3*WSZ, mk, C2, Ho, Ho, ssS[2], statsB);
    k_bnfinal8<<<1, CH, 0, stream>>>(statsB, cnts + i+1, rg2 + i*CH, rb2 + i*CH, ssS[3]);

    k_resid<<<(sites*CH+255)/256, 256, 0, stream>>>(C2, B, mk, ssS[3], ssS[1], B, sites);
    X = B;
  }

  // ---- final 1x1 + BN + ReLU -> d_out (f32 NCHW) ----
  k_final<<<(NB*256*CH + 255)/256, 256, 0, stream>>>(X, final_w, M[4], S0);
  k_bnstatsF<<<32, 192, 0, stream>>>(S0, M[4], statsF, NB*256);
  k_bnfinalA<<<1, CH, 0, stream>>>(statsF, cnts + 4, final_g, final_b, ssA);
  k_bnapply_out<<<(NB*CH*256 + 255)/256, 256, 0, stream>>>(S0, M[4], ssA, outF);

  // ---- tail ----
  k_tail<<<16, 256, 0, stream>>>(maskI, outF);
}

// Round 11
// 1696.243 us; speedup vs baseline: 2.2204x; 1.0562x over previous
//
#include <hip/hip_runtime.h>
#include <hip/hip_bf16.h>

typedef __hip_bfloat16 bf16;
typedef unsigned short u16;
typedef unsigned int u32;
typedef unsigned char u8;
typedef __attribute__((ext_vector_type(8))) short bf16x8;
typedef __attribute__((ext_vector_type(4))) float f32x4;

#define NB 8
#define CH 192
#define WSZ (CH*CH*9)

// Activations channels-last: A[b][y][x][c], bf16. Convs write RAW outputs and
// accumulate masked per-batch BN stats into per-layer slots; consumers rebuild
// the affine in their prologue (no standalone BN kernels on the critical path).

static __device__ __forceinline__ float bf2f(bf16 v){ return __bfloat162float(v); }
static __device__ __forceinline__ u16 f2bu(float f){
  union { bf16 h; u16 u; } cv; cv.h = __float2bfloat16(f); return cv.u;
}
static __device__ __forceinline__ float u2f(u16 u){
  union { bf16 h; u16 u; } cv; cv.u = u; return __bfloat162float(cv.h);
}
static __device__ __forceinline__ u32 pk2bf(float a, float b){
  union { __hip_bfloat162 h; u32 u; } cv;
  cv.h = __float22bfloat162_rn(make_float2(a, b));
  return cv.u;
}

// in-LDS per-channel affine rebuild from per-batch stats slot
static __device__ __forceinline__ void build_ss(const float* __restrict__ stIn,
        const float* __restrict__ g, const float* __restrict__ bb,
        const float* __restrict__ cnt, float* scs, float* shs, int t){
  if(t < CH){
    float s = 0.f, s2 = 0.f;
#pragma unroll
    for(int b=0;b<NB;b++){ s += stIn[b*384 + t]; s2 += stIn[b*384 + 192 + t]; }
    float n = fmaxf(*cnt, 1.0f);
    float mean = s/n;
    float var = fmaxf(s2/n - mean*mean, 0.f);
    float rstd = rsqrtf(var + 1e-5f);
    float sc = g[t]*rstd;
    scs[t] = sc;
    shs[t] = bb[t] - mean*sc;
  }
}

// 8-channel affine on a uint4 of bf16 (sc/sh 16B-aligned)
template<int RELU>
static __device__ __forceinline__ uint4 affine8(uint4 v, const float* scp, const float* shp){
  float4 sa = *(const float4*)(scp);
  float4 sb = *(const float4*)(scp+4);
  float4 ha = *(const float4*)(shp);
  float4 hb = *(const float4*)(shp+4);
  u16* pv = (u16*)&v;
  float f0, f1;
  f0 = u2f(pv[0])*sa.x + ha.x; f1 = u2f(pv[1])*sa.y + ha.y;
  if(RELU){ f0 = fmaxf(f0,0.f); f1 = fmaxf(f1,0.f); }
  ((u32*)&v)[0] = pk2bf(f0, f1);
  f0 = u2f(pv[2])*sa.z + ha.z; f1 = u2f(pv[3])*sa.w + ha.w;
  if(RELU){ f0 = fmaxf(f0,0.f); f1 = fmaxf(f1,0.f); }
  ((u32*)&v)[1] = pk2bf(f0, f1);
  f0 = u2f(pv[4])*sb.x + hb.x; f1 = u2f(pv[5])*sb.y + hb.y;
  if(RELU){ f0 = fmaxf(f0,0.f); f1 = fmaxf(f1,0.f); }
  ((u32*)&v)[2] = pk2bf(f0, f1);
  f0 = u2f(pv[6])*sb.z + hb.z; f1 = u2f(pv[7])*sb.w + hb.w;
  if(RELU){ f0 = fmaxf(f0,0.f); f1 = fmaxf(f1,0.f); }
  ((u32*)&v)[3] = pk2bf(f0, f1);
  return v;
}

// ---------------- utility kernels ----------------

__global__ void k_zero(float* p, int n){
  int i = blockIdx.x*blockDim.x + threadIdx.x;
  if(i < n) p[i] = 0.f;
}

__global__ void k_fill(float* p, int n, float v){
  int i = blockIdx.x*blockDim.x + threadIdx.x;
  if(i < n) p[i] = v;
}

__global__ void k_mask0(const int* __restrict__ mask, u8* __restrict__ m0){
  int i = blockIdx.x*blockDim.x + threadIdx.x;
  if(i >= NB*65536) return;
  int b = i >> 16; int p = i & 65535;
  int y = p >> 8, x = p & 255;
  int patch = (y >> 4)*16 + (x >> 4);
  m0[i] = (u8)(1 - mask[b*256 + patch]);
}

__global__ void k_maskdown(const u8* __restrict__ mi, u8* __restrict__ mo,
                           int Ho, int Wo, int Hi, int Wi){
  int i = blockIdx.x*blockDim.x + threadIdx.x;
  int total = NB*Ho*Wo; if(i >= total) return;
  int b = i/(Ho*Wo); int p = i%(Ho*Wo);
  int oy = p/Wo, ox = p%Wo;
  u8 v = 0;
  for(int ky=0; ky<3; ky++){
    int iy = oy*2 + ky - 1; if(iy < 0 || iy >= Hi) continue;
    for(int kx=0; kx<3; kx++){
      int ix = ox*2 + kx - 1; if(ix < 0 || ix >= Wi) continue;
      u8 t = mi[(b*Hi + iy)*Wi + ix]; if(t > v) v = t;
    }
  }
  mo[i] = v;
}

__global__ void k_count(const u8* __restrict__ m, int n, float* cnt){
  int i = blockIdx.x*blockDim.x + threadIdx.x;
  int stride = gridDim.x*blockDim.x;
  int local = 0;
  for(int j=i; j<n; j+=stride) local += m[j];
  for(int o=32; o>0; o>>=1) local += __shfl_down(local, o, 64);
  if((threadIdx.x & 63) == 0 && local) atomicAdd(cnt, (float)local);
}

// ---------------- stem BN stats (images NCHW f32) -> statsF ----------------

__global__ __launch_bounds__(256) void k_stemstats2(const float* __restrict__ im,
        const u8* __restrict__ m0, const float* __restrict__ sw,
        float* __restrict__ stats){
  int c = blockIdx.x;
  int chunk = blockIdx.y;
  float w0 = sw[c*3+0], w1 = sw[c*3+1], w2 = sw[c*3+2];
  float s = 0.f, s2 = 0.f;
  int start = chunk*4096;
  for(int j = start + threadIdx.x; j < start + 4096; j += 256){
    if(m0[j]){
      int b = j >> 16, p = j & 65535;
      float d = w0*im[(size_t)(b*3+0)*65536 + p]
              + w1*im[(size_t)(b*3+1)*65536 + p]
              + w2*im[(size_t)(b*3+2)*65536 + p];
      s += d; s2 += d*d;
    }
  }
  for(int o=32; o>0; o>>=1){ s += __shfl_down(s, o, 64); s2 += __shfl_down(s2, o, 64); }
  __shared__ float sh[8];
  int w = threadIdx.x >> 6;
  if((threadIdx.x & 63) == 0){ sh[w] = s; sh[4+w] = s2; }
  __syncthreads();
  if(threadIdx.x == 0){
    float ts = 0.f, t2 = 0.f;
    for(int k=0;k<4;k++){ ts += sh[k]; t2 += sh[4+k]; }
    atomicAdd(&stats[c], ts);
    atomicAdd(&stats[CH + c], t2);
  }
}

__global__ void k_fold(const float* __restrict__ sw, const float* __restrict__ ssA,
                       float* __restrict__ swf){
  int c = threadIdx.x; if(c >= CH) return;
  float sc = ssA[c];
  swf[c*4+0] = sc*sw[c*3+0];
  swf[c*4+1] = sc*sw[c*3+1];
  swf[c*4+2] = sc*sw[c*3+2];
  swf[c*4+3] = ssA[CH+c];
}

// all 16 weight sets at once -> Wb16 slots [stage*4+sel][tap][co][ci] bf16
__global__ void k_repack16(const float* __restrict__ dw1, const float* __restrict__ dw2,
                           const float* __restrict__ rw1, const float* __restrict__ rw2,
                           bf16* __restrict__ wb){
  int i = blockIdx.x*blockDim.x + threadIdx.x;
  if(i >= 16*WSZ) return;
  int stage = i/(4*WSZ);
  int sel = (i/WSZ)%4;
  int r = i%WSZ;
  const float* w = (sel==0)?dw1 : (sel==1)?dw2 : (sel==2)?rw1 : rw2;
  float val = w[(size_t)stage*WSZ + r];
  int tap = r%9; int ci = (r/9)%CH; int co = r/(9*CH);
  wb[(size_t)(stage*4+sel)*WSZ + tap*CH*CH + co*CH + ci] = __float2bfloat16(val);
}

// single 384-float stats finalize (stem, final 1x1), self-zeroing
__global__ void k_bnfinalA(float* __restrict__ stats, const float* __restrict__ cnt,
                           const float* __restrict__ g, const float* __restrict__ bb,
                           float* __restrict__ ss){
  int c = threadIdx.x; if(c >= CH) return;
  float n = fmaxf(*cnt, 1.0f);
  float mean = stats[c]/n;
  float var = fmaxf(stats[CH + c]/n - mean*mean, 0.f);
  float rstd = rsqrtf(var + 1e-5f);
  float sc = g[c]*rstd;
  ss[c] = sc;
  ss[CH + c] = bb[c] - mean*sc;
  stats[c] = 0.f; stats[CH + c] = 0.f;
}

// ---------------- shared conv epilogues ----------------

static __device__ __forceinline__ void epi_stats(f32x4 (&acc)[4][3], const u8* sm,
        float* __restrict__ statsB, int b, int co0, int l15, int q, int lane){
  float s[3], s2[3];
#pragma unroll
  for(int nt=0;nt<3;nt++){ s[nt]=0.f; s2[nt]=0.f; }
#pragma unroll
  for(int mt=0;mt<4;mt++){
#pragma unroll
    for(int r=0;r<4;r++){
      int site = mt*16 + q*4 + r;
      float mv = (float)sm[site];
#pragma unroll
      for(int nt=0;nt<3;nt++){
        float v = acc[mt][nt][r]*mv;
        s[nt] += v; s2[nt] += v*v;
      }
    }
  }
#pragma unroll
  for(int nt=0;nt<3;nt++){
    s[nt]  += __shfl_down(s[nt], 32, 64);  s[nt]  += __shfl_down(s[nt], 16, 64);
    s2[nt] += __shfl_down(s2[nt], 32, 64); s2[nt] += __shfl_down(s2[nt], 16, 64);
  }
  if(lane < 16){
#pragma unroll
    for(int nt=0;nt<3;nt++){
      int co = co0 + nt*16 + l15;
      atomicAdd(&statsB[b*384 + co], s[nt]);
      atomicAdd(&statsB[b*384 + 192 + co], s2[nt]);
    }
  }
}

// full 64-site epilogue (obuf needs 64*212 u16 = 27136 B)
static __device__ __forceinline__ void epi_store(f32x4 (&acc)[4][3], u16* obuf,
        u16* __restrict__ out, int b, int oy0, int ox0, int Ho, int Wo,
        int t, int co0, int l15, int q){
  __syncthreads();
#pragma unroll
  for(int mt=0;mt<4;mt++){
#pragma unroll
    for(int nt=0;nt<3;nt++){
      int co = co0 + nt*16 + l15;
#pragma unroll
      for(int r=0;r<4;r++){
        int site = mt*16 + q*4 + r;
        obuf[site*212 + co] = f2bu(acc[mt][nt][r]);
      }
    }
  }
  __syncthreads();
  for(int e=t; e<3072; e+=256){
    int r = e/384; int off = (e%384)*4;
    int sx = off/CH, co = off%CH;
    ushort4 v = *(const ushort4*)&obuf[(r*8+sx)*212 + co];
    *(ushort4*)(out + ((size_t)(b*Ho+oy0+r)*Wo + ox0)*CH + off) = v;
  }
}

// half epilogue: 32 sites (rows half*4 .. half*4+3); obuf needs 32*212 u16 = 13568 B
static __device__ __forceinline__ void epi_store_half(f32x4 (&acc)[4][3], u16* obuf,
        u16* __restrict__ out, int b, int oy0, int ox0, int Ho, int Wo,
        int t, int co0, int l15, int q, int half){
  __syncthreads();
#pragma unroll
  for(int mi=0; mi<2; mi++){
    int mt = half*2 + mi;
#pragma unroll
    for(int nt=0;nt<3;nt++){
      int co = co0 + nt*16 + l15;
#pragma unroll
      for(int r=0;r<4;r++){
        int site = mi*16 + q*4 + r;   // local 0..31
        obuf[site*212 + co] = f2bu(acc[mt][nt][r]);
      }
    }
  }
  __syncthreads();
  for(int e=t; e<1536; e+=256){
    int r = e/384; int off = (e%384)*4;
    int sx = off/CH, co = off%CH;
    ushort4 v = *(const ushort4*)&obuf[(r*8+sx)*212 + co];
    *(ushort4*)(out + ((size_t)(b*Ho+oy0+half*4+r)*Wo + ox0)*CH + off) = v;
  }
}

// ---------------- s1 3x3 conv: LDS-staged, consumer-affine + producer-stats ----------------
#define CIP 200
template<int RELU>
__global__ __launch_bounds__(256) void k_convm(const bf16* __restrict__ in,
        const bf16* __restrict__ wb, const u8* __restrict__ mk,
        bf16* __restrict__ out, int Ho, int Wo,
        const float* __restrict__ stIn, const float* __restrict__ gIn,
        const float* __restrict__ bIn, const float* __restrict__ cnt,
        float* __restrict__ statsB){
  __shared__ __align__(16) u16 tile[10*10*CIP];   // 40 KB; obuf aliased
  __shared__ __align__(16) float scs[CH], shs[CH];
  __shared__ u8 sm[64];
  __shared__ u8 wmk[100];
  __shared__ int anyact;
  const int t = threadIdx.x;
  const int b = blockIdx.z;
  const int ox0 = blockIdx.x*8, oy0 = blockIdx.y*8;
  const int gy0 = oy0 - 1, gx0 = ox0 - 1;

  if(t == 0) anyact = 0;
  __syncthreads();
  if(t < 64){
    int r = t >> 3, c = t & 7;
    u8 mv = mk[(b*Ho + oy0 + r)*Wo + ox0 + c];
    sm[t] = mv;
    if(mv) anyact = 1;
  } else if(t < 164){
    int e = t - 64;
    int y = e/10, x = e%10;
    int gy = gy0 + y, gx = gx0 + x;
    u8 mv = 0;
    if(gy >= 0 && gy < Ho && gx >= 0 && gx < Wo) mv = mk[(b*Ho+gy)*Wo+gx];
    wmk[e] = mv;
  }
  __syncthreads();
  if(!anyact) return;

  build_ss(stIn, gIn, bIn, cnt, scs, shs, t);
  __syncthreads();

  const u16* inp = (const u16*)in;
  for(int u=t; u<2400; u+=256){
    int y = u/240; int rem = u%240; int x = rem/24; int cu = rem%24;
    int gy = gy0 + y, gx = gx0 + x;
    uint4 v = {0u,0u,0u,0u};
    if(wmk[y*10+x]){
      v = *(const uint4*)(inp + ((size_t)(b*Ho+gy)*Wo+gx)*CH + cu*8);
      v = affine8<RELU>(v, &scs[cu*8], &shs[cu*8]);
    }
    *(uint4*)&tile[(y*10+x)*CIP + cu*8] = v;
  }
  __syncthreads();

  const int w = t >> 6;
  const int l = t & 63;
  const int l15 = l & 15, q = l >> 4;
  f32x4 acc[4][3];
#pragma unroll
  for(int mt=0;mt<4;mt++)
#pragma unroll
    for(int nt=0;nt<3;nt++) acc[mt][nt] = (f32x4){0.f,0.f,0.f,0.f};

  int sy[4], sx[4];
#pragma unroll
  for(int mt=0;mt<4;mt++){ int s = mt*16 + l15; sy[mt] = s>>3; sx[mt] = s&7; }
  const int co0 = w*48;

  for(int tap=0; tap<9; tap++){
    const int ky = tap/3, kx = tap%3;
    const u16* tb[4];
#pragma unroll
    for(int mt=0;mt<4;mt++)
      tb[mt] = &tile[((sy[mt]+ky)*10 + sx[mt]+kx)*CIP + q*8];
    const u16* wt0 = (const u16*)(wb + (size_t)tap*CH*CH);
#pragma unroll
    for(int c=0;c<6;c++){
      bf16x8 a[4], bb[3];
#pragma unroll
      for(int mt=0;mt<4;mt++) a[mt] = *(const bf16x8*)(tb[mt] + c*32);
#pragma unroll
      for(int nt=0;nt<3;nt++){
        int co = co0 + nt*16 + l15;
        bb[nt] = *(const bf16x8*)(wt0 + co*CH + c*32 + q*8);
      }
#pragma unroll
      for(int mt=0;mt<4;mt++)
#pragma unroll
        for(int nt=0;nt<3;nt++)
          acc[mt][nt] = __builtin_amdgcn_mfma_f32_16x16x32_bf16(a[mt], bb[nt], acc[mt][nt], 0, 0, 0);
    }
  }
  epi_stats(acc, sm, statsB, b, co0, l15, q, l);
  epi_store(acc, tile, (u16*)out, b, oy0, ox0, Ho, Wo, t, co0, l15, q);
}

// ---------------- s2 3x3 conv: direct-global A-frags (input pre-masked X) ----------------

__global__ __launch_bounds__(256) void k_convs2(const bf16* __restrict__ in,
        const bf16* __restrict__ wb, const u8* __restrict__ mk,
        bf16* __restrict__ out, int Ho, int Wo, float* __restrict__ statsB){
  __shared__ __align__(16) u16 obuf[64*212];
  __shared__ u8 sm[64];
  __shared__ int anyact;
  const int t = threadIdx.x;
  const int b = blockIdx.z;
  const int ox0 = blockIdx.x*8, oy0 = blockIdx.y*8;
  const int Hi = Ho*2, Wi = Wo*2;

  if(t == 0) anyact = 0;
  __syncthreads();
  if(t < 64){
    int r = t >> 3, c = t & 7;
    u8 mv = mk[(b*Ho + oy0 + r)*Wo + ox0 + c];
    sm[t] = mv;
    if(mv) anyact = 1;
  }
  __syncthreads();
  if(!anyact) return;

  const u16* inp = (const u16*)in;
  const int w = t >> 6;
  const int l = t & 63;
  const int l15 = l & 15, q = l >> 4;
  f32x4 acc[4][3];
#pragma unroll
  for(int mt=0;mt<4;mt++)
#pragma unroll
    for(int nt=0;nt<3;nt++) acc[mt][nt] = (f32x4){0.f,0.f,0.f,0.f};

  int gyb[4], gxb[4];
#pragma unroll
  for(int mt=0;mt<4;mt++){
    int s = mt*16 + l15;
    gyb[mt] = (oy0 + (s>>3))*2 - 1;
    gxb[mt] = (ox0 + (s&7))*2 - 1;
  }
  const int co0 = w*48;
  const bf16x8 zro = {0,0,0,0,0,0,0,0};

  for(int tap=0; tap<9; tap++){
    const int ky = tap/3, kx = tap%3;
    const u16* ap[4]; bool av[4];
#pragma unroll
    for(int mt=0;mt<4;mt++){
      int gy = gyb[mt] + ky, gx = gxb[mt] + kx;
      av[mt] = (gy >= 0 && gy < Hi && gx >= 0 && gx < Wi);
      ap[mt] = inp + ((size_t)(b*Hi+gy)*Wi+gx)*CH + q*8;
    }
    const u16* wt0 = (const u16*)(wb + (size_t)tap*CH*CH);
#pragma unroll
    for(int c=0;c<6;c++){
      bf16x8 a[4], bb[3];
#pragma unroll
      for(int mt=0;mt<4;mt++) a[mt] = av[mt] ? *(const bf16x8*)(ap[mt] + c*32) : zro;
#pragma unroll
      for(int nt=0;nt<3;nt++){
        int co = co0 + nt*16 + l15;
        bb[nt] = *(const bf16x8*)(wt0 + co*CH + c*32 + q*8);
      }
#pragma unroll
      for(int mt=0;mt<4;mt++)
#pragma unroll
        for(int nt=0;nt<3;nt++)
          acc[mt][nt] = __builtin_amdgcn_mfma_f32_16x16x32_bf16(a[mt], bb[nt], acc[mt][nt], 0, 0, 0);
    }
  }
  epi_stats(acc, sm, statsB, b, co0, l15, q, l);
  epi_store(acc, obuf, (u16*)out, b, oy0, ox0, Ho, Wo, t, co0, l15, q);
}

// ---------------- stage-0 (256->128 s2) with fused stem, 3x64-ci passes ----------------
#define CIP0 76
__global__ __launch_bounds__(256) void k_conv0m(const float* __restrict__ im,
        const float* __restrict__ swf, const u8* __restrict__ m0,
        const bf16* __restrict__ wb, const u8* __restrict__ mk,
        bf16* __restrict__ out, float* __restrict__ statsB){
  __shared__ __align__(16) u16 tile[289*CIP0];   // 43928 B; obuf(13568 B) aliased
  __shared__ float rgbs[3][292];
  __shared__ u8 mts[292];
  __shared__ u8 sm[64];
  __shared__ int anyact;
  const int t = threadIdx.x;
  const int b = blockIdx.z;
  const int ox0 = blockIdx.x*8, oy0 = blockIdx.y*8;

  if(t == 0) anyact = 0;
  __syncthreads();
  if(t < 64){
    int r = t >> 3, c = t & 7;
    u8 mv = mk[(b*128 + oy0 + r)*128 + ox0 + c];
    sm[t] = mv;
    if(mv) anyact = 1;
  }
  __syncthreads();
  if(!anyact) return;

  const int gy0 = oy0*2 - 1, gx0 = ox0*2 - 1;
  for(int e=t; e<289; e+=256){
    int r = e/17, c = e%17;
    int gy = gy0 + r, gx = gx0 + c;
    float r_=0.f, g_=0.f, bl=0.f; u8 mv=0;
    if(gy >= 0 && gy < 256 && gx >= 0 && gx < 256){
      int pi = gy*256 + gx;
      mv = m0[b*65536 + pi];
      r_ = im[(size_t)(b*3+0)*65536 + pi];
      g_ = im[(size_t)(b*3+1)*65536 + pi];
      bl = im[(size_t)(b*3+2)*65536 + pi];
    }
    rgbs[0][e]=r_; rgbs[1][e]=g_; rgbs[2][e]=bl; mts[e]=mv;
  }

  const int w = t >> 6;
  const int l = t & 63;
  const int l15 = l & 15, q = l >> 4;
  f32x4 acc[4][3];
#pragma unroll
  for(int mt=0;mt<4;mt++)
#pragma unroll
    for(int nt=0;nt<3;nt++) acc[mt][nt] = (f32x4){0.f,0.f,0.f,0.f};

  int siy[4], six[4];
#pragma unroll
  for(int mt=0;mt<4;mt++){ int s = mt*16 + l15; siy[mt] = (s>>3)*2; six[mt] = (s&7)*2; }
  const int co0 = w*48;

  for(int h=0; h<3; h++){
    __syncthreads();
    // stem eval for 64 channels into tile[site][ci_local]
    for(int e=t; e<289*32; e+=256){
      int site = e >> 5, cp = e & 31;
      int ci = h*64 + cp*2;
      float4 w0 = *(const float4*)&swf[ci*4];
      float4 w1 = *(const float4*)&swf[(ci+1)*4];
      float r_ = rgbs[0][site], g_ = rgbs[1][site], b_ = rgbs[2][site];
      u32 pk = 0u;
      if(mts[site]){
        float d0 = fmaxf(w0.x*r_ + w0.y*g_ + w0.z*b_ + w0.w, 0.f);
        float d1 = fmaxf(w1.x*r_ + w1.y*g_ + w1.z*b_ + w1.w, 0.f);
        pk = pk2bf(d0, d1);
      }
      *(u32*)&tile[site*CIP0 + cp*2] = pk;
    }
    __syncthreads();
    for(int tap=0; tap<9; tap++){
      const int ky = tap/3, kx = tap%3;
      const u16* tb[4];
#pragma unroll
      for(int mt=0;mt<4;mt++)
        tb[mt] = &tile[((siy[mt]+ky)*17 + six[mt]+kx)*CIP0 + q*8];
      const u16* wt0 = (const u16*)(wb + (size_t)tap*CH*CH);
#pragma unroll
      for(int c=0;c<2;c++){
        bf16x8 a[4], bb[3];
#pragma unroll
        for(int mt=0;mt<4;mt++) a[mt] = *(const bf16x8*)(tb[mt] + c*32);
#pragma unroll
        for(int nt=0;nt<3;nt++){
          int co = co0 + nt*16 + l15;
          bb[nt] = *(const bf16x8*)(wt0 + co*CH + h*64 + c*32 + q*8);
        }
#pragma unroll
        for(int mt=0;mt<4;mt++)
#pragma unroll
          for(int nt=0;nt<3;nt++)
            acc[mt][nt] = __builtin_amdgcn_mfma_f32_16x16x32_bf16(a[mt], bb[nt], acc[mt][nt], 0, 0, 0);
      }
    }
  }
  epi_stats(acc, sm, statsB, b, co0, l15, q, l);
  epi_store_half(acc, tile, (u16*)out, b, oy0, ox0, 128, 128, t, co0, l15, q, 0);
  epi_store_half(acc, tile, (u16*)out, b, oy0, ox0, 128, 128, t, co0, l15, q, 1);
}

// ---------------- residual combine: X = relu(affD(D)*m + affB(B)*m), 8 elems/thread ----------------

__global__ __launch_bounds__(256) void k_resid(const bf16* __restrict__ xD,
        const bf16* __restrict__ xB, const u8* __restrict__ m,
        const float* __restrict__ stD, const float* __restrict__ gD, const float* __restrict__ bD,
        const float* __restrict__ stB, const float* __restrict__ gB, const float* __restrict__ bB,
        const float* __restrict__ cnt, bf16* __restrict__ out, int sites){
  __shared__ __align__(16) float scD[CH], shD[CH], scB[CH], shB[CH];
  const int t = threadIdx.x;
  build_ss(stD, gD, bD, cnt, scD, shD, t);
  build_ss(stB, gB, bB, cnt, scB, shB, t);
  __syncthreads();
  int idx = blockIdx.x*256 + t;
  int total = sites*24;           // 24 groups of 8 channels per site
  if(idx >= total) return;
  int si = idx/24; int c0 = (idx%24)*8;
  float mv = (float)m[si];
  const u16* pd = (const u16*)xD + (size_t)si*CH + c0;
  const u16* pb = (const u16*)xB + (size_t)si*CH + c0;
  uint4 vd = *(const uint4*)pd;
  uint4 vb = *(const uint4*)pb;
  u16* dd = (u16*)&vd; u16* db = (u16*)&vb;
  uint4 vo;
#pragma unroll
  for(int j=0;j<4;j++){
    int c = c0 + j*2;
    float f0 = (u2f(dd[j*2  ])*scD[c  ] + shD[c  ])*mv + (u2f(db[j*2  ])*scB[c  ] + shB[c  ])*mv;
    float f1 = (u2f(dd[j*2+1])*scD[c+1] + shD[c+1])*mv + (u2f(db[j*2+1])*scB[c+1] + shB[c+1])*mv;
    ((u32*)&vo)[j] = pk2bf(fmaxf(f0, 0.f), fmaxf(f1, 0.f));
  }
  *(uint4*)((u16*)out + (size_t)si*CH + c0) = vo;
}

// ---------------- final 1x1 conv at 16x16 + standalone stats ----------------

__global__ void k_final(const bf16* __restrict__ in, const float* __restrict__ w,
                        const u8* __restrict__ m4, bf16* __restrict__ out){
  int i = blockIdx.x*blockDim.x + threadIdx.x;
  if(i >= NB*256*CH) return;
  int co = i % CH; int si = i / CH;
  if(!m4[si]) return;
  float acc = 0.f;
  const bf16* ib = in + (size_t)si*CH;
  for(int ci=0; ci<CH; ci++)
    acc += w[co*CH + ci]*bf2f(ib[ci]);
  out[i] = __float2bfloat16(acc);
}

__global__ __launch_bounds__(192) void k_bnstatsF(const bf16* __restrict__ x,
        const u8* __restrict__ m, float* __restrict__ stats, int sites){
  int c = threadIdx.x;
  float s = 0.f, s2 = 0.f;
  for(int si = blockIdx.x; si < sites; si += gridDim.x){
    if(m[si]){
      float v = bf2f(x[(size_t)si*CH + c]);
      s += v; s2 += v*v;
    }
  }
  atomicAdd(&stats[c], s);
  atomicAdd(&stats[CH + c], s2);
}

__global__ void k_bnapply_out(const bf16* __restrict__ x, const u8* __restrict__ m,
                              const float* __restrict__ ss, float* __restrict__ out){
  int i = blockIdx.x*blockDim.x + threadIdx.x;
  if(i >= NB*CH*256) return;
  int p = i % 256; int c = (i/256) % CH; int b = i/(256*CH);
  int si = b*256 + p;
  float v = bf2f(x[(size_t)si*CH + c])*ss[c] + ss[CH + c];
  v *= (float)m[si];
  v = fmaxf(v, 0.f);
  out[i] = v;
}

// ---------------- tail ----------------

__global__ void k_tail(const int* __restrict__ mask, float* __restrict__ out){
  int i = blockIdx.x*blockDim.x + threadIdx.x;
  if(i < 2048){
    out[393216 + i] = (float)mask[i];
  } else if(i < 4096){
    int j = i - 2048;
    out[395264 + j] = (float)(j & 255);
  }
}

// ---------------- host orchestration ----------------

extern "C" void kernel_launch(void* const* d_in, const int* in_sizes, int n_in,
                              void* d_out, int out_size, void* d_ws, size_t ws_size,
                              hipStream_t stream){
  const float* images = (const float*)d_in[0];
  const int*   maskI  = (const int*)d_in[1];
  const float* stem_w = (const float*)d_in[2];
  const float* stem_g = (const float*)d_in[3];
  const float* stem_b = (const float*)d_in[4];
  const float* dw1 = (const float*)d_in[5];
  const float* dg1 = (const float*)d_in[6];
  const float* db1 = (const float*)d_in[7];
  const float* dw2 = (const float*)d_in[8];
  const float* dg2 = (const float*)d_in[9];
  const float* db2 = (const float*)d_in[10];
  const float* rw1 = (const float*)d_in[11];
  const float* rg1 = (const float*)d_in[12];
  const float* rb1 = (const float*)d_in[13];
  const float* rw2 = (const float*)d_in[14];
  const float* rg2 = (const float*)d_in[15];
  const float* rb2 = (const float*)d_in[16];
  const float* final_w = (const float*)d_in[17];
  const float* final_g = (const float*)d_in[18];
  const float* final_b = (const float*)d_in[19];
  float* outF = (float*)d_out;

  char* wsp = (char*)d_ws;
  auto alloc = [&](size_t bytes)->char*{
    char* p = wsp; wsp += (bytes + 255) & ~(size_t)255; return p;
  };
  bf16* S0 = (bf16*)alloc((size_t)NB*CH*16384*2);
  bf16* S1 = (bf16*)alloc((size_t)NB*CH*16384*2);
  bf16* S2 = (bf16*)alloc((size_t)NB*CH*16384*2);
  int Hs[5] = {256,128,64,32,16};
  u8* M[5];
  for(int l=0;l<5;l++) M[l] = (u8*)alloc((size_t)NB*Hs[l]*Hs[l]);
  bf16*  Wb16 = (bf16*)alloc((size_t)16*WSZ*2);      // 10.6 MB
  float* swf = (float*)alloc(CH*4*4);
  float* statsB16 = (float*)alloc((size_t)16*NB*384*4);   // per-layer per-batch stats
  float* statsF = (float*)alloc(384*4);
  float* ssA   = (float*)alloc(2*CH*4);
  float* cnts  = (float*)alloc(8*4);
  size_t need = (size_t)(wsp - (char*)d_ws);

  if(ws_size < need){
    k_fill<<<(393216+255)/256, 256, 0, stream>>>(outF, 393216, 777.0f);
    k_tail<<<16, 256, 0, stream>>>(maskI, outF);
    return;
  }

  // ---- zero stats (ws poisoned every call) + repack all weights once ----
  int nz = 16*NB*384 + 384;
  k_zero<<<(nz+255)/256, 256, 0, stream>>>(statsB16, nz);
  k_zero<<<1, 32, 0, stream>>>(cnts, 8);
  k_repack16<<<(16*WSZ+255)/256, 256, 0, stream>>>(dw1, dw2, rw1, rw2, Wb16);

  // ---- mask pyramid + counts ----
  k_mask0<<<(NB*65536+255)/256, 256, 0, stream>>>(maskI, M[0]);
  for(int l=1;l<5;l++){
    int total = NB*Hs[l]*Hs[l];
    k_maskdown<<<(total+255)/256, 256, 0, stream>>>(M[l-1], M[l], Hs[l], Hs[l], Hs[l-1], Hs[l-1]);
  }
  for(int l=0;l<5;l++){
    int n = NB*Hs[l]*Hs[l];
    int blocks = (n + 256*64 - 1)/(256*64); if(blocks < 1) blocks = 1; if(blocks > 256) blocks = 256;
    k_count<<<blocks, 256, 0, stream>>>(M[l], n, cnts + l);
  }

  // ---- stem BN params + fold ----
  k_stemstats2<<<dim3(CH, 128), 256, 0, stream>>>(images, M[0], stem_w, statsF);
  k_bnfinalA<<<1, CH, 0, stream>>>(statsF, cnts + 0, stem_g, stem_b, ssA);
  k_fold<<<1, CH, 0, stream>>>(stem_w, ssA, swf);

  // ---- 4 stages ----
  bf16* X = nullptr;
  for(int i=0;i<4;i++){
    int Ho = Hs[i+1];
    int sites = NB*Ho*Ho;
    const u8* mk = M[i+1];
    const float* cnt = cnts + i + 1;
    bf16* A = S0;
    bf16* B = (i % 2 == 0) ? S1 : S2;
    bf16* C2 = (i == 0) ? S2 : X;
    dim3 g(Ho/8, Ho/8, NB);
    const bf16* W0 = Wb16 + (size_t)(i*4+0)*WSZ;
    const bf16* W1 = Wb16 + (size_t)(i*4+1)*WSZ;
    const bf16* W2 = Wb16 + (size_t)(i*4+2)*WSZ;
    const bf16* W3 = Wb16 + (size_t)(i*4+3)*WSZ;
    float* st0 = statsB16 + (size_t)(i*4+0)*NB*384;
    float* st1 = statsB16 + (size_t)(i*4+1)*NB*384;
    float* st2 = statsB16 + (size_t)(i*4+2)*NB*384;
    float* st3 = statsB16 + (size_t)(i*4+3)*NB*384;

    if(i == 0){
      dim3 g0(16, 16, NB);
      k_conv0m<<<g0, 256, 0, stream>>>(images, swf, M[0], W0, M[1], A, st0);
    } else {
      k_convs2<<<g, 256, 0, stream>>>(X, W0, mk, A, Ho, Ho, st0);
    }
    k_convm<1><<<g, 256, 0, stream>>>(A, W1, mk, B, Ho, Ho,
        st0, dg1 + i*CH, db1 + i*CH, cnt, st1);
    k_convm<0><<<g, 256, 0, stream>>>(B, W2, mk, A, Ho, Ho,
        st1, dg2 + i*CH, db2 + i*CH, cnt, st2);
    k_convm<1><<<g, 256, 0, stream>>>(A, W3, mk, C2, Ho, Ho,
        st2, rg1 + i*CH, rb1 + i*CH, cnt, st3);
    k_resid<<<(sites*24 + 255)/256, 256, 0, stream>>>(C2, B, mk,
        st3, rg2 + i*CH, rb2 + i*CH,
        st1, dg2 + i*CH, db2 + i*CH, cnt, B, sites);
    X = B;
  }

  // ---- final 1x1 + BN + ReLU -> d_out (f32 NCHW) ----
  k_final<<<(NB*256*CH + 255)/256, 256, 0, stream>>>(X, final_w, M[4], S0);
  k_bnstatsF<<<32, 192, 0, stream>>>(S0, M[4], statsF, NB*256);
  k_bnfinalA<<<1, CH, 0, stream>>>(statsF, cnts + 4, final_g, final_b, ssA);
  k_bnapply_out<<<(NB*CH*256 + 255)/256, 256, 0, stream>>>(S0, M[4], ssA, outF);

  // ---- tail ----
  k_tail<<<16, 256, 0, stream>>>(maskI, outF);
}